// Round 7
// baseline (7036.620 us; speedup 1.0000x reference)
//
#include <hip/hip_runtime.h>

typedef unsigned short ushort_t;
typedef unsigned int uint_t;
typedef unsigned long long u64_t;
typedef __bf16 bf16x8 __attribute__((ext_vector_type(8)));
typedef float f32x4 __attribute__((ext_vector_type(4)));

#define T_STEPS 512
#define NWG 256
#define LDS_P 1032  // padded LDS row stride in bf16 elements
#define GL_P 33     // padded gate-tile stride in f32

__device__ __forceinline__ float bf2f(ushort_t u) {
  union { unsigned u; float f; } v; v.u = ((unsigned)u) << 16; return v.f;
}
__device__ __forceinline__ ushort_t f2bf(float f) {
  union { float f; unsigned u; } v; v.f = f;
  unsigned r = (v.u + 0x7FFFu + ((v.u >> 16) & 1u)) >> 16;
  return (ushort_t)r;
}
__device__ __forceinline__ uint_t pack2(float a, float b) {
  return (uint_t)f2bf(a) | ((uint_t)f2bf(b) << 16);
}
__device__ __forceinline__ float sigf(float x) {
  return 1.0f / (1.0f + __expf(-x));
}

// ---------------------------------------------------------------------------
// fp32 -> bf16, vectorized, grid-stride
// ---------------------------------------------------------------------------
__global__ void __launch_bounds__(256) cvt_f32_bf16(
    const float* __restrict__ in, ushort_t* __restrict__ outp, int n4) {
  int i = blockIdx.x * 256 + threadIdx.x;
  const int stride = gridDim.x * 256;
  for (; i < n4; i += stride) {
    float4 v = ((const float4*)in)[i];
    ushort4 o;
    o.x = f2bf(v.x); o.y = f2bf(v.y); o.z = f2bf(v.z); o.w = f2bf(v.w);
    ((ushort4*)outp)[i] = o;
  }
}

// ---------------------------------------------------------------------------
// W1 -> per-WG permuted bf16: Wp1 row pr = [wgl=pr>>5][c=pr&31],
// src row = (c>>3)*1024 + wgl*8 + (c&7). One block per row, 256 thr x float4.
// ---------------------------------------------------------------------------
__global__ void __launch_bounds__(256) cvt_permW1(
    const float* __restrict__ W1, ushort_t* __restrict__ Wp1) {
  int pr = blockIdx.x;
  int wgl = pr >> 5, c = pr & 31;
  int srcr = ((c >> 3) << 10) + (wgl << 3) + (c & 7);
  const float4* s = (const float4*)(W1 + (size_t)srcr * 1024);
  ushort4* d = (ushort4*)(Wp1 + (size_t)pr * 1024);
  float4 v = s[threadIdx.x];
  ushort4 o;
  o.x = f2bf(v.x); o.y = f2bf(v.y); o.z = f2bf(v.z); o.w = f2bf(v.w);
  d[threadIdx.x] = o;
}

// ---------------------------------------------------------------------------
// GEMM: xg0p[m][pc] = sum_k X[m][k]*W0[n][k] + bi0[n], with column permute
// pc = ((n&1023)>>3)*32 + (n&7)*4 + (n>>10).  X fp32 (reg-staged cvt), W bf16.
// grid (M/128, 32), 256 thr.
// ---------------------------------------------------------------------------
__global__ void __launch_bounds__(256, 1) gemm_xg(
    const float* __restrict__ X, const ushort_t* __restrict__ Wm,
    const float* __restrict__ bi, ushort_t* __restrict__ outp) {
  __shared__ char smem[65536];  // 2 x (16KB A + 16KB B)
  const int tid = threadIdx.x;
  const int lane = tid & 63, w = tid >> 6;
  const int m0 = blockIdx.x * 128, n0 = blockIdx.y * 128;
  const int wr = w >> 1, wc = w & 1;
  const int lr = lane & 15, kg = lane >> 4;
  const int ar_ = tid & 127;       // A-staging row
  const int abq = (tid >> 7) * 4;  // A-staging 16B-block quad

  f32x4 acc[4][4] = {};
  float4 fa[8];

  auto stageA_issue = [&](int kt) {
    const float* src = X + (size_t)(m0 + ar_) * 1024 + kt * 64 + abq * 8;
#pragma unroll
    for (int i = 0; i < 4; ++i) {
      fa[2 * i] = *(const float4*)(src + i * 8);
      fa[2 * i + 1] = *(const float4*)(src + i * 8 + 4);
    }
  };
  auto stageA_write = [&](int p) {
    char* sA = smem + p * 32768;
#pragma unroll
    for (int i = 0; i < 4; ++i) {
      int blk = abq + i;
      uint4 o;
      o.x = pack2(fa[2 * i].x, fa[2 * i].y);
      o.y = pack2(fa[2 * i].z, fa[2 * i].w);
      o.z = pack2(fa[2 * i + 1].x, fa[2 * i + 1].y);
      o.w = pack2(fa[2 * i + 1].z, fa[2 * i + 1].w);
      *(uint4*)(sA + ar_ * 128 + ((blk ^ (ar_ & 7)) << 4)) = o;
    }
  };
  auto stageB = [&](int kt, int p) {
    const int ks = kt * 64;
    char* sB = smem + p * 32768 + 16384;
#pragma unroll
    for (int i = 0; i < 4; ++i) {
      int wi = w * 4 + i;
      int e = wi * 64 + lane;
      int row = e >> 3, pb = e & 7;
      int kb = pb ^ (row & 7);
      const ushort_t* gB = Wm + (size_t)(n0 + row) * 1024 + ks + kb * 8;
      __builtin_amdgcn_global_load_lds(
          (const __attribute__((address_space(1))) void*)gB,
          (__attribute__((address_space(3))) void*)(sB + wi * 1024), 16, 0, 0);
    }
  };

  stageA_issue(0);
  stageB(0, 0);
  stageA_write(0);
  __syncthreads();
#pragma unroll 1
  for (int kt = 0; kt < 16; ++kt) {
    const int p = kt & 1;
    if (kt < 15) { stageA_issue(kt + 1); stageB(kt + 1, p ^ 1); }
    const char* sA = smem + p * 32768;
    const char* sB = sA + 16384;
#pragma unroll
    for (int k2 = 0; k2 < 2; ++k2) {
      bf16x8 af[4], bf[4];
#pragma unroll
      for (int mt = 0; mt < 4; ++mt) {
        int ar = wr * 64 + mt * 16 + lr;
        int kb = k2 * 4 + kg;
        af[mt] = *(const bf16x8*)(sA + ar * 128 + ((kb ^ (ar & 7)) << 4));
      }
#pragma unroll
      for (int nt = 0; nt < 4; ++nt) {
        int br = wc * 64 + nt * 16 + lr;
        int kb = k2 * 4 + kg;
        bf[nt] = *(const bf16x8*)(sB + br * 128 + ((kb ^ (br & 7)) << 4));
      }
#pragma unroll
      for (int mt = 0; mt < 4; ++mt)
#pragma unroll
        for (int nt = 0; nt < 4; ++nt)
          acc[mt][nt] = __builtin_amdgcn_mfma_f32_16x16x32_bf16(
              af[mt], bf[nt], acc[mt][nt], 0, 0, 0);
    }
    if (kt < 15) stageA_write(p ^ 1);
    __syncthreads();
  }
#pragma unroll
  for (int nt = 0; nt < 4; ++nt) {
    int gc = n0 + wc * 64 + nt * 16 + lr;
    int pc = ((gc & 1023) >> 3) * 32 + (gc & 7) * 4 + (gc >> 10);
    float bv = bi[gc];
#pragma unroll
    for (int mt = 0; mt < 4; ++mt) {
#pragma unroll
      for (int r = 0; r < 4; ++r) {
        int gr = m0 + wr * 64 + mt * 16 + kg * 4 + r;
        outp[(size_t)gr * 4096 + pc] = f2bf(acc[mt][nt][r] + bv);
      }
    }
  }
}

// ---------------------------------------------------------------------------
// Fused 2-layer persistent recurrence. 256 WGs x 256 thr (1/CU).
// WGs 0..127: layer 0 (xg0p precomputed). WGs 128..255: layer 1, lagging one
// step; computes W1 projection in-kernel (B-frags from permuted Wp1, L2-hot).
// 513 global steps; flag-array barrier; h exchange via sc0/sc1 L3 ops.
// gates i,o,z,f:  c = c*f + z - i;  h = sig(c) - o.
// ---------------------------------------------------------------------------
__global__ void __launch_bounds__(256, 1) fused_rec(
    const ushort_t* __restrict__ xg0p, const float* __restrict__ R0,
    const float* __restrict__ R1, const ushort_t* __restrict__ Wp1,
    const float* __restrict__ bh0, const float* __restrict__ bi1,
    const float* __restrict__ bh1, const float* __restrict__ h0_all,
    const float* __restrict__ c0_all, float* __restrict__ out_f,
    float* __restrict__ hfinb, float* __restrict__ cfinb,
    ushort_t* __restrict__ hpp0, ushort_t* __restrict__ hpp1,
    uint_t* __restrict__ flags) {
  extern __shared__ char smem[];
  ushort_t* Rl = (ushort_t*)smem;                 // [32][LDS_P] bf16
  ushort_t* hl = (ushort_t*)(smem + 66048);       // [32][LDS_P] bf16
  float* gl = (float*)(smem + 132096);            // [32][GL_P] f32

  const int tid = threadIdx.x;
  const int wg = blockIdx.x;
  const int layer = wg >> 7;
  const int wgl = wg & 127;
  const int j0 = wgl * 8;
  const int lane = tid & 63, w = tid >> 6;
  const int mt16 = (w >> 1) << 4, nt16 = (w & 1) << 4;
  const int lr = lane & 15, kg = lane >> 4;
  const int b = tid >> 3, jj = tid & 7;
  const int srow = tid >> 7;          // staging row parity
  const int selem = (tid & 127) * 8;  // staging elem offset

  // one-time: R slice -> LDS (cvt fp32->bf16). col c: gate c>>3, hid j0+(c&7)
  const float* Rsrc = layer ? R1 : R0;
#pragma unroll 2
  for (int it = 0; it < 16; ++it) {
    int idx = it * 256 + tid;
    int c = idx >> 7, k8 = (idx & 127) * 8;
    int gr = (c >> 3) * 1024 + j0 + (c & 7);
    const float* src = Rsrc + (size_t)gr * 1024 + k8;
    float4 f0 = *(const float4*)src;
    float4 f1 = *(const float4*)(src + 4);
    uint4 o;
    o.x = pack2(f0.x, f0.y); o.y = pack2(f0.z, f0.w);
    o.z = pack2(f1.x, f1.y); o.w = pack2(f1.z, f1.w);
    *(uint4*)(Rl + c * LDS_P + k8) = o;
  }

  float bhv[4];
#pragma unroll
  for (int g = 0; g < 4; ++g) {
    int gi = g * 1024 + j0 + jj;
    bhv[g] = layer ? (bi1[gi] + bh1[gi]) : bh0[gi];
  }
  const int cidx = b * 1024 + j0 + jj;
  float c_st = c0_all[layer * 32768 + cidx];
  float* hfin = hfinb + layer * 32768;
  float* cfin = cfinb + layer * 32768;
  uint_t* hppd = (uint_t*)(layer ? hpp1 : hpp0);

  for (int s = 0; s <= T_STEPS; ++s) {
    const bool active = layer ? (s >= 1) : (s < T_STEPS);
    if (active) {
      const int t = layer ? (s - 1) : s;
      float hv;
      if (layer == 0) {
        // xg: one coalesced dwordx2 (4 gates packed by the permuted GEMM)
        uint2 xgu = *(const uint2*)(xg0p + (size_t)(t * 32 + b) * 4096 +
                                    wgl * 32 + jj * 4);
        if (t == 0) {
#pragma unroll 2
          for (int it = 0; it < 16; ++it) {
            int idx = it * 256 + tid;
            int r = idx >> 7, k8 = (idx & 127) * 8;
            const float* src = h0_all + (size_t)r * 1024 + k8;
            float4 f0 = *(const float4*)src;
            float4 f1 = *(const float4*)(src + 4);
            uint4 o;
            o.x = pack2(f0.x, f0.y); o.y = pack2(f0.z, f0.w);
            o.z = pack2(f1.x, f1.y); o.w = pack2(f1.z, f1.w);
            *(uint4*)(hl + r * LDS_P + k8) = o;
          }
        } else {
          uint4 hv4[16];
          const char* hsrc = (const char*)hpp0 + (((t - 1) & 1) << 16);
#pragma unroll
          for (int it = 0; it < 16; ++it)
            asm volatile("global_load_dwordx4 %0, %1, off sc0 sc1"
                         : "=v"(hv4[it]) : "v"(hsrc + it * 4096 + tid * 16));
          asm volatile("s_waitcnt vmcnt(0)" ::: "memory");
#pragma unroll
          for (int it = 0; it < 16; ++it)
            *(uint4*)(hl + (it * 2 + srow) * LDS_P + selem) = hv4[it];
        }
        __syncthreads();
        f32x4 acc = {0.f, 0.f, 0.f, 0.f};
#pragma unroll 8
        for (int kt = 0; kt < 32; ++kt) {
          int k = kt * 32 + kg * 8;
          bf16x8 a = *(const bf16x8*)(hl + (mt16 + lr) * LDS_P + k);
          bf16x8 bb = *(const bf16x8*)(Rl + (nt16 + lr) * LDS_P + k);
          acc = __builtin_amdgcn_mfma_f32_16x16x32_bf16(a, bb, acc, 0, 0, 0);
        }
#pragma unroll
        for (int r = 0; r < 4; ++r)
          gl[(mt16 + kg * 4 + r) * GL_P + nt16 + lr] = acc[r];
        __syncthreads();
        float pre0 = gl[b * GL_P + 0 + jj] + bf2f((ushort_t)(xgu.x & 0xffff)) + bhv[0];
        float pre1 = gl[b * GL_P + 8 + jj] + bf2f((ushort_t)(xgu.x >> 16)) + bhv[1];
        float pre2 = gl[b * GL_P + 16 + jj] + bf2f((ushort_t)(xgu.y & 0xffff)) + bhv[2];
        float pre3 = gl[b * GL_P + 24 + jj] + bf2f((ushort_t)(xgu.y >> 16)) + bhv[3];
        float ig = sigf(pre0), og = sigf(pre1), zg = sigf(pre2), fg = sigf(pre3);
        c_st = c_st * fg + zg - ig;
        hv = sigf(c_st) - og;
      } else {
        // ---- layer 1: R1 @ h1(t-1) + W1 @ h0(t), hl reused sequentially ----
        uint4 h1v4[16], h0v4[16];
        const char* h0src = (const char*)hpp0 + ((t & 1) << 16);
        if (t == 0) {
#pragma unroll
          for (int it = 0; it < 16; ++it)
            asm volatile("global_load_dwordx4 %0, %1, off sc0 sc1"
                         : "=v"(h0v4[it]) : "v"(h0src + it * 4096 + tid * 16));
          // h1(-1) = h0_all layer-1 slice (fp32 cvt) -> hl
#pragma unroll 2
          for (int it = 0; it < 16; ++it) {
            int idx = it * 256 + tid;
            int r = idx >> 7, k8 = (idx & 127) * 8;
            const float* src = h0_all + 32768 + (size_t)r * 1024 + k8;
            float4 f0 = *(const float4*)src;
            float4 f1 = *(const float4*)(src + 4);
            uint4 o;
            o.x = pack2(f0.x, f0.y); o.y = pack2(f0.z, f0.w);
            o.z = pack2(f1.x, f1.y); o.w = pack2(f1.z, f1.w);
            *(uint4*)(hl + r * LDS_P + k8) = o;
          }
        } else {
          const char* h1src = (const char*)hpp1 + (((t - 1) & 1) << 16);
#pragma unroll
          for (int it = 0; it < 16; ++it)
            asm volatile("global_load_dwordx4 %0, %1, off sc0 sc1"
                         : "=v"(h1v4[it]) : "v"(h1src + it * 4096 + tid * 16));
#pragma unroll
          for (int it = 0; it < 16; ++it)
            asm volatile("global_load_dwordx4 %0, %1, off sc0 sc1"
                         : "=v"(h0v4[it]) : "v"(h0src + it * 4096 + tid * 16));
          // first 16 issued (h1) are guaranteed drained by vmcnt(16)
          asm volatile("s_waitcnt vmcnt(16)" ::: "memory");
#pragma unroll
          for (int it = 0; it < 16; ++it)
            *(uint4*)(hl + (it * 2 + srow) * LDS_P + selem) = h1v4[it];
        }
        __syncthreads();
        f32x4 acc = {0.f, 0.f, 0.f, 0.f};
#pragma unroll 8
        for (int kt = 0; kt < 32; ++kt) {
          int k = kt * 32 + kg * 8;
          bf16x8 a = *(const bf16x8*)(hl + (mt16 + lr) * LDS_P + k);
          bf16x8 bb = *(const bf16x8*)(Rl + (nt16 + lr) * LDS_P + k);
          acc = __builtin_amdgcn_mfma_f32_16x16x32_bf16(a, bb, acc, 0, 0, 0);
        }
        asm volatile("s_waitcnt vmcnt(0)" ::: "memory");  // h0 arrived
        __syncthreads();  // everyone done reading hl (R-part)
#pragma unroll
        for (int it = 0; it < 16; ++it)
          *(uint4*)(hl + (it * 2 + srow) * LDS_P + selem) = h0v4[it];
        __syncthreads();
        const ushort_t* wrow = Wp1 + ((size_t)wgl * 32 + nt16 + lr) * 1024;
#pragma unroll 8
        for (int kt = 0; kt < 32; ++kt) {
          int k = kt * 32 + kg * 8;
          bf16x8 a = *(const bf16x8*)(hl + (mt16 + lr) * LDS_P + k);
          bf16x8 bb = *(const bf16x8*)(wrow + k);
          acc = __builtin_amdgcn_mfma_f32_16x16x32_bf16(a, bb, acc, 0, 0, 0);
        }
#pragma unroll
        for (int r = 0; r < 4; ++r)
          gl[(mt16 + kg * 4 + r) * GL_P + nt16 + lr] = acc[r];
        __syncthreads();
        float pre0 = gl[b * GL_P + 0 + jj] + bhv[0];
        float pre1 = gl[b * GL_P + 8 + jj] + bhv[1];
        float pre2 = gl[b * GL_P + 16 + jj] + bhv[2];
        float pre3 = gl[b * GL_P + 24 + jj] + bhv[3];
        float ig = sigf(pre0), og = sigf(pre1), zg = sigf(pre2), fg = sigf(pre3);
        c_st = c_st * fg + zg - ig;
        hv = sigf(c_st) - og;
        out_f[(size_t)t * 32768 + cidx] = hv;  // fp32 h1 output
      }
      // publish h(t) -> ping-pong (packed bf16 pairs, L3-coherent)
      ushort_t hb = f2bf(hv);
      int partner = __shfl_down((int)hb, 1, 64);
      if ((tid & 1) == 0) {
        uint_t packed = (uint_t)hb | (((uint_t)(unsigned short)partner) << 16);
        uint_t* dst = hppd + (((t & 1) << 14) + (cidx >> 1));
        asm volatile("global_store_dword %0, %1, off sc0 sc1"
                     :: "v"(dst), "v"(packed) : "memory");
      }
      if (t == T_STEPS - 1) {
        hfin[cidx] = hv;
        cfin[cidx] = c_st;
      }
    }
    if (s < T_STEPS) {
      const uint_t gen1 = (uint_t)s + 1u;
      asm volatile("s_waitcnt vmcnt(0)" ::: "memory");  // drain publishes
      __syncthreads();
      if (tid == 0)
        __hip_atomic_store(&flags[wg], gen1, __ATOMIC_RELAXED,
                           __HIP_MEMORY_SCOPE_AGENT);
      while (__hip_atomic_load(&flags[tid], __ATOMIC_RELAXED,
                               __HIP_MEMORY_SCOPE_AGENT) < gen1) {
        __builtin_amdgcn_s_sleep(1);
      }
      __syncthreads();
      asm volatile("" ::: "memory");
    }
  }
}

// ---------------------------------------------------------------------------
extern "C" void kernel_launch(void* const* d_in, const int* in_sizes, int n_in,
                              void* d_out, int out_size, void* d_ws,
                              size_t ws_size, hipStream_t stream) {
  (void)in_sizes; (void)n_in; (void)out_size; (void)ws_size;
  const float* x = (const float*)d_in[0];
  const float* h0 = (const float*)d_in[1];
  const float* c0 = (const float*)d_in[2];
  const float* W0 = (const float*)d_in[3];
  const float* R0 = (const float*)d_in[4];
  const float* bi0 = (const float*)d_in[5];
  const float* bh0 = (const float*)d_in[6];
  const float* W1 = (const float*)d_in[7];
  const float* R1 = (const float*)d_in[8];
  const float* bi1 = (const float*)d_in[9];
  const float* bh1 = (const float*)d_in[10];
  float* outp = (float*)d_out;

  // ws: Wbf0 8MB | Wp1 8MB | xg0p 128MB | hpp0 128KB | hpp1 128KB | flags
  // total ~144.3MB (R6 ran T_CH=512 => ws_size >= ~168MB).
  char* ws = (char*)d_ws;
  ushort_t* Wbf0 = (ushort_t*)ws;
  ushort_t* Wp1 = (ushort_t*)(ws + 8388608);
  ushort_t* xg0p = (ushort_t*)(ws + 16777216);
  ushort_t* hpp0 = (ushort_t*)(ws + 16777216 + 134217728);
  ushort_t* hpp1 = (ushort_t*)((char*)hpp0 + 131072);
  uint_t* flags = (uint_t*)((char*)hpp1 + 131072);

  const int REC_LDS = 2 * (32 * LDS_P * 2) + 32 * GL_P * 4;  // 136320 B
  (void)hipFuncSetAttribute((const void*)fused_rec,
                            hipFuncAttributeMaxDynamicSharedMemorySize,
                            REC_LDS);
  (void)hipMemsetAsync(flags, 0, NWG * sizeof(uint_t), stream);

  float* hfinb = outp + 16777216;     // [2][32][1024]
  float* cfinb = hfinb + 65536;       // [2][32][1024]

  cvt_f32_bf16<<<dim3(1024), dim3(256), 0, stream>>>(W0, Wbf0, 1048576);
  cvt_permW1<<<dim3(4096), dim3(256), 0, stream>>>(W1, Wp1);
  gemm_xg<<<dim3(128, 32), dim3(256), 0, stream>>>(x, Wbf0, bi0, xg0p);
  fused_rec<<<dim3(NWG), dim3(256), REC_LDS, stream>>>(
      xg0p, R0, R1, Wp1, bh0, bi1, bh1, h0, c0, outp, hfinb, cfinb,
      hpp0, hpp1, flags);
}